// Round 14
// baseline (298.332 us; speedup 1.0000x reference)
//
#include <hip/hip_runtime.h>

// GCN: h = mean-aggregate(feature over incoming edges, fallback feature if deg==0)
//      out = relu(h @ W^T + b)
// N=50000 nodes, E=1600000 edges, D=128.
// R14: fillB (global scatter, 10x write amp) -> fillL (LDS-staged per-sub-bucket
//      window, coalesced write-out). NPBK=6256 so 16x391-node sub-buckets nest.

#define NN 50000
#define EE 1600000
#define DD 128
#define NSTRIP 3125    // 50000 / 16
#define NBUCK 8
#define NPBK 6256      // nodes per bucket (= 16 sub-buckets x 391)
#define NPSB 391       // nodes per sub-bucket
#define WCAP 14500     // LDS window capacity (ints); avg need ~12500
#define WCHUNK 1024    // edges per wave-chunk
#define NW 1563        // ceil(EE / WCHUNK)
#define NPB 391        // ceil(NW / 4) blocks for p1/p3
#define NSC 49         // ceil(50001 / 1024) scan blocks
#define FB_PER 32      // hist blocks per bucket

typedef __attribute__((ext_vector_type(8))) short bf16x8;
typedef __attribute__((ext_vector_type(8))) unsigned short u16x8;
typedef __attribute__((ext_vector_type(4))) float f32x4;

static __device__ __forceinline__ short f2bf(float f) {
  union { float f; unsigned u; } x; x.f = f;
  unsigned r = (x.u + 0x7FFF + ((x.u >> 16) & 1)) >> 16;
  return (short)(r & 0xFFFF);
}

// ---- P1: per-wave-chunk bucket counts, atomic-free ----
__global__ __launch_bounds__(256) void p1_count(
    const int* __restrict__ dst, int* __restrict__ bc) {
  const int wv = threadIdx.x >> 6, lane = threadIdx.x & 63;
  const int w = blockIdx.x * 4 + wv;
  if (w >= NW) return;
  const int base = w * WCHUNK;

  int c0 = 0, c1 = 0, c2 = 0, c3 = 0, c4 = 0, c5 = 0, c6 = 0, c7 = 0;
#pragma unroll
  for (int it = 0; it < 4; ++it) {
    int idx = base + it * 256 + lane * 4;
#pragma unroll
    for (int j = 0; j < 4; ++j) {
      int e = idx + j;
      if (e < EE) {
        int b = dst[e] / NPBK;
        c0 += (b == 0); c1 += (b == 1); c2 += (b == 2); c3 += (b == 3);
        c4 += (b == 4); c5 += (b == 5); c6 += (b == 6); c7 += (b == 7);
      }
    }
  }
#pragma unroll
  for (int d = 1; d < 64; d <<= 1) {
    c0 += __shfl_xor(c0, d, 64); c1 += __shfl_xor(c1, d, 64);
    c2 += __shfl_xor(c2, d, 64); c3 += __shfl_xor(c3, d, 64);
    c4 += __shfl_xor(c4, d, 64); c5 += __shfl_xor(c5, d, 64);
    c6 += __shfl_xor(c6, d, 64); c7 += __shfl_xor(c7, d, 64);
  }
  if (lane < NBUCK) {
    int out = 0;
    out += (lane == 0) ? c0 : 0; out += (lane == 1) ? c1 : 0;
    out += (lane == 2) ? c2 : 0; out += (lane == 3) ? c3 : 0;
    out += (lane == 4) ? c4 : 0; out += (lane == 5) ? c5 : 0;
    out += (lane == 6) ? c6 : 0; out += (lane == 7) ? c7 : 0;
    bc[lane * NW + w] = out;
  }
}

// ---- P2: generic single-block exclusive scan (length n) ----
__global__ __launch_bounds__(1024) void p2_scan(
    const int* __restrict__ in, int* __restrict__ out, int n) {
  __shared__ int ws[16];
  __shared__ int s_off;
  const int wv = threadIdx.x >> 6, lane = threadIdx.x & 63;
  if (threadIdx.x == 0) s_off = 0;
  __syncthreads();
  for (int base = 0; base < n; base += 1024) {
    int i = base + threadIdx.x;
    int v = (i < n) ? in[i] : 0;
    int x = v;
#pragma unroll
    for (int d = 1; d < 64; d <<= 1) { int t = __shfl_up(x, d, 64); if (lane >= d) x += t; }
    if (lane == 63) ws[wv] = x;
    __syncthreads();
    if (threadIdx.x < 16) {
      int w = ws[threadIdx.x];
#pragma unroll
      for (int d = 1; d < 16; d <<= 1) { int t = __shfl_up(w, d, 16); if (threadIdx.x >= d) w += t; }
      ws[threadIdx.x] = w;
    }
    __syncthreads();
    int off = s_off + ((wv == 0) ? 0 : ws[wv - 1]);
    if (i < n) out[i] = off + x - v;
    __syncthreads();
    if (threadIdx.x == 0) s_off += ws[15];
    __syncthreads();
  }
}

// ---- P3: ballot multi-split partition into 8 dst-buckets, atomic-free ----
__global__ __launch_bounds__(256) void p3_partition(
    const int* __restrict__ src, const int* __restrict__ dst,
    const int* __restrict__ bo, int* __restrict__ psrc, int* __restrict__ pdst) {
  const int wv = threadIdx.x >> 6, lane = threadIdx.x & 63;
  const int w = blockIdx.x * 4 + wv;
  if (w >= NW) return;
  const int base = w * WCHUNK;

  int cur0 = bo[0 * NW + w], cur1 = bo[1 * NW + w], cur2 = bo[2 * NW + w],
      cur3 = bo[3 * NW + w], cur4 = bo[4 * NW + w], cur5 = bo[5 * NW + w],
      cur6 = bo[6 * NW + w], cur7 = bo[7 * NW + w];

  const unsigned long long below = (lane == 63) ? 0x7FFFFFFFFFFFFFFFull
                                                : ((1ull << lane) - 1ull);
#pragma unroll 4
  for (int it = 0; it < 16; ++it) {
    int e = base + it * 64 + lane;
    bool v = e < EE;
    int s = v ? src[e] : 0;
    int d = v ? dst[e] : 0;
    int b = v ? (d / NPBK) : NBUCK;

    int pos = 0;
    unsigned long long m;
    m = __ballot(b == 0);
    pos += (b == 0) ? (cur0 + __popcll(m & below)) : 0; cur0 += __popcll(m);
    m = __ballot(b == 1);
    pos += (b == 1) ? (cur1 + __popcll(m & below)) : 0; cur1 += __popcll(m);
    m = __ballot(b == 2);
    pos += (b == 2) ? (cur2 + __popcll(m & below)) : 0; cur2 += __popcll(m);
    m = __ballot(b == 3);
    pos += (b == 3) ? (cur3 + __popcll(m & below)) : 0; cur3 += __popcll(m);
    m = __ballot(b == 4);
    pos += (b == 4) ? (cur4 + __popcll(m & below)) : 0; cur4 += __popcll(m);
    m = __ballot(b == 5);
    pos += (b == 5) ? (cur5 + __popcll(m & below)) : 0; cur5 += __popcll(m);
    m = __ballot(b == 6);
    pos += (b == 6) ? (cur6 + __popcll(m & below)) : 0; cur6 += __popcll(m);
    m = __ballot(b == 7);
    pos += (b == 7) ? (cur7 + __popcll(m & below)) : 0; cur7 += __popcll(m);

    if (v) { psrc[pos] = s; pdst[pos] = d; }
  }
}

// ---- histB: bucketed deg histogram (XCD-local atomics) ----
__global__ __launch_bounds__(256) void histB(
    const int* __restrict__ pdst, const int* __restrict__ bo,
    int* __restrict__ deg_i) {
  const int b   = blockIdx.x & 7;
  const int sub = blockIdx.x >> 3;
  const int start = bo[b * NW];
  const int end   = (b == NBUCK - 1) ? EE : bo[(b + 1) * NW];
  for (int e = start + sub * 256 + threadIdx.x; e < end; e += FB_PER * 256) {
    atomicAdd(&deg_i[pdst[e]], 1);
  }
}

// ---- S1/S2/S3: parallel exclusive scan of deg -> row_start ----
__global__ __launch_bounds__(1024) void s1_bsum(
    const int* __restrict__ deg_i, int* __restrict__ bsum) {
  __shared__ int ws[16];
  int i = blockIdx.x * 1024 + threadIdx.x;
  int v = (i < NN) ? deg_i[i] : 0;
#pragma unroll
  for (int d = 1; d < 64; d <<= 1) v += __shfl_xor(v, d, 64);
  int wv = threadIdx.x >> 6, lane = threadIdx.x & 63;
  if (lane == 0) ws[wv] = v;
  __syncthreads();
  if (threadIdx.x == 0) {
    int s = 0;
#pragma unroll
    for (int k = 0; k < 16; ++k) s += ws[k];
    bsum[blockIdx.x] = s;
  }
}

__global__ __launch_bounds__(64) void s2_scan(int* __restrict__ bsum) {
  int t = threadIdx.x;
  int v = (t < NSC) ? bsum[t] : 0;
  int x = v;
#pragma unroll
  for (int d = 1; d < 64; d <<= 1) { int u = __shfl_up(x, d, 64); if (t >= d) x += u; }
  if (t < NSC) bsum[t] = x - v;   // exclusive
}

__global__ __launch_bounds__(1024) void s3_apply(
    const int* __restrict__ deg_i, const int* __restrict__ bsum,
    int* __restrict__ row_start) {
  __shared__ int ws[16];
  int i = blockIdx.x * 1024 + threadIdx.x;
  int wv = threadIdx.x >> 6, lane = threadIdx.x & 63;
  int v = (i < NN) ? deg_i[i] : 0;
  int x = v;
#pragma unroll
  for (int d = 1; d < 64; d <<= 1) { int t = __shfl_up(x, d, 64); if (lane >= d) x += t; }
  if (lane == 63) ws[wv] = x;
  __syncthreads();
  if (threadIdx.x < 16) {
    int w = ws[threadIdx.x];
#pragma unroll
    for (int d = 1; d < 16; d <<= 1) { int t = __shfl_up(w, d, 16); if (threadIdx.x >= d) w += t; }
    ws[threadIdx.x] = w;
  }
  __syncthreads();
  int off = bsum[blockIdx.x] + ((wv == 0) ? 0 : ws[wv - 1]);
  if (i <= NN) row_start[i] = off + x - v;
}

// ---- fillL: LDS-staged CSR fill; one wg per 391-node sub-bucket ----
// blockIdx&7 = parent bucket (XCD affinity); 16 sub-buckets per bucket.
__global__ __launch_bounds__(1024) void fillL(
    const int* __restrict__ psrc, const int* __restrict__ pdst,
    const int* __restrict__ bo, const int* __restrict__ row_start,
    int* __restrict__ csr) {
  __shared__ int win[WCAP];
  __shared__ int cur[NPSB];
  __shared__ int rs[NPSB + 1];
  const int b   = blockIdx.x & 7;
  const int sub = blockIdx.x >> 3;
  const int lo  = b * NPBK + sub * NPSB;
  const int hi  = (lo + NPSB < NN) ? (lo + NPSB) : NN;
  const int nloc = hi - lo;

  for (int i = threadIdx.x; i <= nloc; i += 1024) rs[i] = row_start[lo + i];
  for (int i = threadIdx.x; i < nloc; i += 1024) cur[i] = 0;
  __syncthreads();
  const int base = rs[0];
  const int T    = rs[nloc] - base;
  const int start = bo[b * NW];
  const int end   = (b == NBUCK - 1) ? EE : bo[(b + 1) * NW];

  if (T <= WCAP) {
    for (int e = start + threadIdx.x; e < end; e += 1024) {
      int d = pdst[e];
      if (d >= lo && d < hi) {
        int li = d - lo;
        int p = atomicAdd(&cur[li], 1);
        win[rs[li] - base + p] = psrc[e];
      }
    }
    __syncthreads();
    for (int i = threadIdx.x; i < T; i += 1024) csr[base + i] = win[i];
  } else {
    // safety fallback (statistically unreachable): direct scatter
    for (int e = start + threadIdx.x; e < end; e += 1024) {
      int d = pdst[e];
      if (d >= lo && d < hi) {
        int li = d - lo;
        int p = atomicAdd(&cur[li], 1);
        csr[rs[li] + p] = psrc[e];
      }
    }
  }
}

// ---- feat2bf: f32 feature -> bf16 table (runs after fillL; fb overlays psrc/pdst) ----
__global__ __launch_bounds__(256) void feat2bf_kernel(
    const float* __restrict__ feature, unsigned short* __restrict__ fb) {
  int i = blockIdx.x * 256 + threadIdx.x;   // one float4 per thread
  if (i < NN * DD / 4) {
    float4 v = ((const float4*)feature)[i];
    short4 o;
    o.x = f2bf(v.x); o.y = f2bf(v.y); o.z = f2bf(v.z); o.w = f2bf(v.w);
    ((short4*)fb)[i] = o;
  }
}

// ---- aggregate: wave per node, u16x8/lane, 16 lanes/row, 4 edges in flight ----
__global__ __launch_bounds__(256) void aggregate_bf16(
    const unsigned short* __restrict__ fb,   // bf16 [NN][128]
    const int* __restrict__ row_start,
    const int* __restrict__ csr_src,
    unsigned short* __restrict__ hb) {
  const int wave = threadIdx.x >> 6;
  const int lane = threadIdx.x & 63;
  int n = blockIdx.x * 4 + wave;
  if (n >= NN) return;

  const int start = row_start[n];
  const int end   = row_start[n + 1];
  const int deg   = end - start;
  const int q  = lane >> 4;   // which of 4 edges in flight
  const int sl = lane & 15;   // 16B slot within 256B row

  const u16x8* fp = (const u16x8*)fb;   // 16 u16x8 per row
  float acc[8];
#pragma unroll
  for (int j = 0; j < 8; ++j) acc[j] = 0.f;

#pragma unroll 4
  for (int e = start + q; e < end; e += 4) {
    int s = csr_src[e];
    u16x8 v = fp[(size_t)s * 16 + sl];
#pragma unroll
    for (int j = 0; j < 8; ++j) {
      union { unsigned u; float f; } c; c.u = ((unsigned)v[j]) << 16;
      acc[j] += c.f;
    }
  }
#pragma unroll
  for (int j = 0; j < 8; ++j) {
    acc[j] += __shfl_xor(acc[j], 16, 64);
    acc[j] += __shfl_xor(acc[j], 32, 64);
  }

  if (q == 0) {
    u16x8 hv;
    if (deg > 0) {
      float inv = 1.0f / (float)deg;
#pragma unroll
      for (int j = 0; j < 8; ++j) hv[j] = (unsigned short)f2bf(acc[j] * inv);
    } else {
      hv = fp[(size_t)n * 16 + sl];   // fallback: bf16(feature) row
    }
    ((u16x8*)hb)[(size_t)n * 16 + sl] = hv;
  }
}

// ---- MFMA GEMM: out = relu(h @ W^T + b) ----
__global__ __launch_bounds__(256) void mfma_gemm_kernel(
    const short* __restrict__ hb,
    const float* __restrict__ weight,
    const float* __restrict__ bias,
    float* __restrict__ out) {
  const int wave = threadIdx.x >> 6;
  const int lane = threadIdx.x & 63;
  const int strip = blockIdx.x * 4 + wave;
  if (strip >= NSTRIP) return;
  const int m0 = strip * 16;
  const int r  = lane & 15;
  const int g  = lane >> 4;

  bf16x8 Bf[8][4];
  float bs[8];
#pragma unroll
  for (int c = 0; c < 8; ++c) {
    bs[c] = bias[c * 16 + r];
#pragma unroll
    for (int t = 0; t < 4; ++t) {
      const float* wp = weight + (c * 16 + r) * DD + t * 32 + g * 8;
      float4 w0 = *(const float4*)(wp);
      float4 w1 = *(const float4*)(wp + 4);
      bf16x8 b;
      b[0] = f2bf(w0.x); b[1] = f2bf(w0.y); b[2] = f2bf(w0.z); b[3] = f2bf(w0.w);
      b[4] = f2bf(w1.x); b[5] = f2bf(w1.y); b[6] = f2bf(w1.z); b[7] = f2bf(w1.w);
      Bf[c][t] = b;
    }
  }

  bf16x8 Af[4];
#pragma unroll
  for (int t = 0; t < 4; ++t) {
    Af[t] = *(const bf16x8*)(hb + (size_t)(m0 + r) * DD + t * 32 + g * 8);
  }

#pragma unroll
  for (int c = 0; c < 8; ++c) {
    f32x4 acc = {0.f, 0.f, 0.f, 0.f};
#pragma unroll
    for (int t = 0; t < 4; ++t) {
      acc = __builtin_amdgcn_mfma_f32_16x16x32_bf16(Af[t], Bf[c][t], acc, 0, 0, 0);
    }
#pragma unroll
    for (int q = 0; q < 4; ++q) {
      int row = m0 + g * 4 + q;
      float v = acc[q] + bs[c];
      out[(size_t)row * DD + c * 16 + r] = v > 0.f ? v : 0.f;
    }
  }
}

extern "C" void kernel_launch(void* const* d_in, const int* in_sizes, int n_in,
                              void* d_out, int out_size, void* d_ws, size_t ws_size,
                              hipStream_t stream) {
  const float* feature = (const float*)d_in[0];
  const int*   src     = (const int*)d_in[1];
  const int*   dst     = (const int*)d_in[2];
  const float* weight  = (const float*)d_in[3];
  const float* bias    = (const float*)d_in[4];
  float* out = (float*)d_out;

  // ws (ints): deg[50000] (unused)[50000] row_start[50001] bc[12504] bo[12504] bsum[64] | hb bf16
  int* deg_i     = (int*)d_ws;
  int* row_start = deg_i + 100000;       // 50001
  int* bc        = row_start + 50004;    // at 150004, 12504
  int* bo        = bc + 12508;           // at 162512, 12504
  int* bsum      = bo + 12508;           // at 175020, 64
  unsigned short* hb = (unsigned short*)(deg_i + 175104);  // byte 700416, 16B aligned

  // d_out as scratch (ints): psrc[E] pdst[E] csr[E] = 19.2MB <= 25.6MB.
  // After fillL, psrc/pdst are dead -> fb (bf16 feature table, 12.8MB) overlays them.
  int* psrc = (int*)d_out;
  int* pdst = psrc + EE;
  int* csr  = pdst + EE;
  unsigned short* fb = (unsigned short*)d_out;

  (void)hipMemsetAsync(d_ws, 0, (size_t)50000 * sizeof(int), stream);  // deg only

  p1_count<<<NPB, 256, 0, stream>>>(dst, bc);
  p2_scan<<<1, 1024, 0, stream>>>(bc, bo, NBUCK * NW);
  p3_partition<<<NPB, 256, 0, stream>>>(src, dst, bo, psrc, pdst);
  histB<<<NBUCK * FB_PER, 256, 0, stream>>>(pdst, bo, deg_i);
  s1_bsum<<<NSC, 1024, 0, stream>>>(deg_i, bsum);
  s2_scan<<<1, 64, 0, stream>>>(bsum);
  s3_apply<<<NSC, 1024, 0, stream>>>(deg_i, bsum, row_start);
  fillL<<<128, 1024, 0, stream>>>(psrc, pdst, bo, row_start, csr);
  feat2bf_kernel<<<(NN * DD / 4 + 255) / 256, 256, 0, stream>>>(feature, fb);
  aggregate_bf16<<<(NN + 3) / 4, 256, 0, stream>>>(fb, row_start, csr, hb);
  mfma_gemm_kernel<<<(NSTRIP + 3) / 4, 256, 0, stream>>>((const short*)hb, weight, bias, out);
}

// Round 15
// 140.181 us; speedup vs baseline: 2.1282x; 2.1282x over previous
//
#include <hip/hip_runtime.h>

// GCN: h = mean-aggregate(feature over incoming edges, fallback feature if deg==0)
//      out = relu(h @ W^T + b)
// N=50000 nodes, E=1600000 edges, D=128.
// R15: single-level 196-way sub-bucket partition (packed u32 edges, d<65536),
//      fillL2 reads only its own region and computes row_start in-kernel.
//      Eliminates 8-way bucket phase, histB, s-chain, memset.

#define NN 50000
#define EE 1600000
#define DD 128
#define NSTRIP 3125    // 50000 / 16
#define GSB 196        // sub-buckets of 256 nodes (50000 = 195*256 + 80)
#define CH2 4096       // edges per wave-chunk
#define NW2 391        // ceil(EE / CH2)
#define NCNT (GSB * NW2)   // 76636
#define NSA 75         // ceil(NCNT / 1024)
#define WCAP 12288     // LDS window (ints); mean need 8163, +45 sigma safe

typedef __attribute__((ext_vector_type(8))) short bf16x8;
typedef __attribute__((ext_vector_type(8))) unsigned short u16x8;
typedef __attribute__((ext_vector_type(4))) float f32x4;

static __device__ __forceinline__ short f2bf(float f) {
  union { float f; unsigned u; } x; x.f = f;
  unsigned r = (x.u + 0x7FFF + ((x.u >> 16) & 1)) >> 16;
  return (short)(r & 0xFFFF);
}

// ---- p1b: per-wave-chunk 196-way counts (LDS counters, low contention) ----
__global__ __launch_bounds__(256) void p1b(
    const int* __restrict__ dst, int* __restrict__ cnt2) {
  __shared__ int cnt[4][GSB];
  const int wv = threadIdx.x >> 6, lane = threadIdx.x & 63;
  const int w = blockIdx.x * 4 + wv;
  const bool act = (w < NW2);
  for (int i = lane; i < GSB; i += 64) cnt[wv][i] = 0;
  __syncthreads();
  if (act) {
    const int base = w * CH2;
#pragma unroll 4
    for (int it = 0; it < 16; ++it) {
      int e0 = base + it * 256 + lane * 4;
      if (e0 < EE) {
        int4 d4 = *(const int4*)(dst + e0);
        atomicAdd(&cnt[wv][((unsigned)d4.x) >> 8], 1);
        atomicAdd(&cnt[wv][((unsigned)d4.y) >> 8], 1);
        atomicAdd(&cnt[wv][((unsigned)d4.z) >> 8], 1);
        atomicAdd(&cnt[wv][((unsigned)d4.w) >> 8], 1);
      }
    }
  }
  __syncthreads();
  if (act) {
    for (int i = lane; i < GSB; i += 64) cnt2[i * NW2 + w] = cnt[wv][i];
  }
}

// ---- sA: per-block sums of cnt2 ----
__global__ __launch_bounds__(1024) void sA_bsum(
    const int* __restrict__ in, int* __restrict__ bsum, int n) {
  __shared__ int ws[16];
  int i = blockIdx.x * 1024 + threadIdx.x;
  int v = (i < n) ? in[i] : 0;
#pragma unroll
  for (int d = 1; d < 64; d <<= 1) v += __shfl_xor(v, d, 64);
  int wv = threadIdx.x >> 6, lane = threadIdx.x & 63;
  if (lane == 0) ws[wv] = v;
  __syncthreads();
  if (threadIdx.x == 0) {
    int s = 0;
#pragma unroll
    for (int k = 0; k < 16; ++k) s += ws[k];
    bsum[blockIdx.x] = s;
  }
}

// ---- sB: generic single-block exclusive scan (in-place safe) ----
__global__ __launch_bounds__(1024) void p2_scan(
    const int* __restrict__ in, int* __restrict__ out, int n) {
  __shared__ int ws[16];
  __shared__ int s_off;
  const int wv = threadIdx.x >> 6, lane = threadIdx.x & 63;
  if (threadIdx.x == 0) s_off = 0;
  __syncthreads();
  for (int base = 0; base < n; base += 1024) {
    int i = base + threadIdx.x;
    int v = (i < n) ? in[i] : 0;
    int x = v;
#pragma unroll
    for (int d = 1; d < 64; d <<= 1) { int t = __shfl_up(x, d, 64); if (lane >= d) x += t; }
    if (lane == 63) ws[wv] = x;
    __syncthreads();
    if (threadIdx.x < 16) {
      int w = ws[threadIdx.x];
#pragma unroll
      for (int d = 1; d < 16; d <<= 1) { int t = __shfl_up(w, d, 16); if (threadIdx.x >= d) w += t; }
      ws[threadIdx.x] = w;
    }
    __syncthreads();
    int off = s_off + ((wv == 0) ? 0 : ws[wv - 1]);
    if (i < n) out[i] = off + x - v;
    __syncthreads();
    if (threadIdx.x == 0) s_off += ws[15];
    __syncthreads();
  }
}

// ---- sC: apply block offsets (exclusive scan finalize, in-place) ----
__global__ __launch_bounds__(1024) void sC_apply(
    int* __restrict__ data, const int* __restrict__ bsum, int n) {
  __shared__ int ws[16];
  int i = blockIdx.x * 1024 + threadIdx.x;
  int wv = threadIdx.x >> 6, lane = threadIdx.x & 63;
  int v = (i < n) ? data[i] : 0;
  int x = v;
#pragma unroll
  for (int d = 1; d < 64; d <<= 1) { int t = __shfl_up(x, d, 64); if (lane >= d) x += t; }
  if (lane == 63) ws[wv] = x;
  __syncthreads();
  if (threadIdx.x < 16) {
    int w = ws[threadIdx.x];
#pragma unroll
    for (int d = 1; d < 16; d <<= 1) { int t = __shfl_up(w, d, 16); if (threadIdx.x >= d) w += t; }
    ws[threadIdx.x] = w;
  }
  __syncthreads();
  int off = bsum[blockIdx.x] + ((wv == 0) ? 0 : ws[wv - 1]);
  if (i < n) data[i] = off + x - v;
}

// ---- p3b: 196-way partition of packed edges (per-wave LDS cursors) ----
__global__ __launch_bounds__(256) void p3b(
    const int* __restrict__ src, const int* __restrict__ dst,
    const int* __restrict__ off2, unsigned int* __restrict__ ss) {
  __shared__ int cur[4][GSB];
  const int wv = threadIdx.x >> 6, lane = threadIdx.x & 63;
  const int w = blockIdx.x * 4 + wv;
  const bool act = (w < NW2);
  if (act) {
    for (int i = lane; i < GSB; i += 64) cur[wv][i] = off2[i * NW2 + w];
  }
  __syncthreads();
  if (act) {
    const int base = w * CH2;
#pragma unroll 2
    for (int it = 0; it < 16; ++it) {
      int e0 = base + it * 256 + lane * 4;
      if (e0 < EE) {
        int4 s4 = *(const int4*)(src + e0);
        int4 d4 = *(const int4*)(dst + e0);
        {
          int p = atomicAdd(&cur[wv][((unsigned)d4.x) >> 8], 1);
          ss[p] = (((unsigned)d4.x) << 16) | (unsigned)s4.x;
        }
        {
          int p = atomicAdd(&cur[wv][((unsigned)d4.y) >> 8], 1);
          ss[p] = (((unsigned)d4.y) << 16) | (unsigned)s4.y;
        }
        {
          int p = atomicAdd(&cur[wv][((unsigned)d4.z) >> 8], 1);
          ss[p] = (((unsigned)d4.z) << 16) | (unsigned)s4.z;
        }
        {
          int p = atomicAdd(&cur[wv][((unsigned)d4.w) >> 8], 1);
          ss[p] = (((unsigned)d4.w) << 16) | (unsigned)s4.w;
        }
      }
    }
  }
}

// ---- fillL2: per-sub-bucket CSR build + row_start (reads ONLY own region) ----
__global__ __launch_bounds__(1024) void fillL2(
    const unsigned int* __restrict__ ss, const int* __restrict__ off2,
    int* __restrict__ csr, int* __restrict__ row_start) {
  __shared__ int win[WCAP];
  __shared__ int cur[256];
  __shared__ int rs[257];
  __shared__ int wsum2[4];
  const int g    = blockIdx.x;
  const int lo   = g * 256;
  const int nloc = (NN - lo < 256) ? (NN - lo) : 256;
  const int ebase = off2[g * NW2];
  const int eend  = (g < GSB - 1) ? off2[(g + 1) * NW2] : EE;
  const int T = eend - ebase;

  if (threadIdx.x < 256) cur[threadIdx.x] = 0;
  __syncthreads();

  // pass 1: per-node degree counts
  for (int e = ebase + threadIdx.x; e < eend; e += 1024) {
    atomicAdd(&cur[(ss[e] >> 16) & 255], 1);
  }
  __syncthreads();

  // scan cur[256] -> rs[0..256]
  int x = 0;
  if (threadIdx.x < 256) {
    const int lane = threadIdx.x & 63;
    x = cur[threadIdx.x];
#pragma unroll
    for (int d = 1; d < 64; d <<= 1) { int t = __shfl_up(x, d, 64); if (lane >= d) x += t; }
    if (lane == 63) wsum2[threadIdx.x >> 6] = x;
  }
  __syncthreads();
  if (threadIdx.x < 256) {
    const int wv2 = threadIdx.x >> 6;
    int pre = 0;
#pragma unroll
    for (int k = 0; k < 4; ++k) pre += (k < wv2) ? wsum2[k] : 0;
    rs[threadIdx.x + 1] = pre + x;
    if (threadIdx.x == 0) rs[0] = 0;
    cur[threadIdx.x] = 0;   // re-zero for pass 2
  }
  __syncthreads();

  // row_start (node-level CSR offsets)
  if (threadIdx.x <= nloc) row_start[lo + threadIdx.x] = ebase + rs[threadIdx.x];

  // pass 2: place into LDS window, then coalesced write-out
  if (T <= WCAP) {
    for (int e = ebase + threadIdx.x; e < eend; e += 1024) {
      unsigned pe = ss[e];
      int li = (pe >> 16) & 255;
      int p = atomicAdd(&cur[li], 1);
      win[rs[li] + p] = (int)(pe & 0xFFFFu);
    }
    __syncthreads();
    for (int i = threadIdx.x; i < T; i += 1024) csr[ebase + i] = win[i];
  } else {
    // safety fallback (statistically unreachable)
    for (int e = ebase + threadIdx.x; e < eend; e += 1024) {
      unsigned pe = ss[e];
      int li = (pe >> 16) & 255;
      int p = atomicAdd(&cur[li], 1);
      csr[ebase + rs[li] + p] = (int)(pe & 0xFFFFu);
    }
  }
}

// ---- feat2bf: f32 feature -> bf16 table ----
__global__ __launch_bounds__(256) void feat2bf_kernel(
    const float* __restrict__ feature, unsigned short* __restrict__ fb) {
  int i = blockIdx.x * 256 + threadIdx.x;   // one float4 per thread
  if (i < NN * DD / 4) {
    float4 v = ((const float4*)feature)[i];
    short4 o;
    o.x = f2bf(v.x); o.y = f2bf(v.y); o.z = f2bf(v.z); o.w = f2bf(v.w);
    ((short4*)fb)[i] = o;
  }
}

// ---- aggregate: wave per node, u16x8/lane, 16 lanes/row, 4 edges in flight ----
__global__ __launch_bounds__(256) void aggregate_bf16(
    const unsigned short* __restrict__ fb,   // bf16 [NN][128]
    const int* __restrict__ row_start,
    const int* __restrict__ csr_src,
    unsigned short* __restrict__ hb) {
  const int wave = threadIdx.x >> 6;
  const int lane = threadIdx.x & 63;
  int n = blockIdx.x * 4 + wave;
  if (n >= NN) return;

  const int start = row_start[n];
  const int end   = row_start[n + 1];
  const int deg   = end - start;
  const int q  = lane >> 4;   // which of 4 edges in flight
  const int sl = lane & 15;   // 16B slot within 256B row

  const u16x8* fp = (const u16x8*)fb;   // 16 u16x8 per row
  float acc[8];
#pragma unroll
  for (int j = 0; j < 8; ++j) acc[j] = 0.f;

#pragma unroll 4
  for (int e = start + q; e < end; e += 4) {
    int s = csr_src[e];
    u16x8 v = fp[(size_t)s * 16 + sl];
#pragma unroll
    for (int j = 0; j < 8; ++j) {
      union { unsigned u; float f; } c; c.u = ((unsigned)v[j]) << 16;
      acc[j] += c.f;
    }
  }
#pragma unroll
  for (int j = 0; j < 8; ++j) {
    acc[j] += __shfl_xor(acc[j], 16, 64);
    acc[j] += __shfl_xor(acc[j], 32, 64);
  }

  if (q == 0) {
    u16x8 hv;
    if (deg > 0) {
      float inv = 1.0f / (float)deg;
#pragma unroll
      for (int j = 0; j < 8; ++j) hv[j] = (unsigned short)f2bf(acc[j] * inv);
    } else {
      hv = fp[(size_t)n * 16 + sl];   // fallback: bf16(feature) row
    }
    ((u16x8*)hb)[(size_t)n * 16 + sl] = hv;
  }
}

// ---- MFMA GEMM: out = relu(h @ W^T + b) ----
__global__ __launch_bounds__(256) void mfma_gemm_kernel(
    const short* __restrict__ hb,
    const float* __restrict__ weight,
    const float* __restrict__ bias,
    float* __restrict__ out) {
  const int wave = threadIdx.x >> 6;
  const int lane = threadIdx.x & 63;
  const int strip = blockIdx.x * 4 + wave;
  if (strip >= NSTRIP) return;
  const int m0 = strip * 16;
  const int r  = lane & 15;
  const int g  = lane >> 4;

  bf16x8 Bf[8][4];
  float bs[8];
#pragma unroll
  for (int c = 0; c < 8; ++c) {
    bs[c] = bias[c * 16 + r];
#pragma unroll
    for (int t = 0; t < 4; ++t) {
      const float* wp = weight + (c * 16 + r) * DD + t * 32 + g * 8;
      float4 w0 = *(const float4*)(wp);
      float4 w1 = *(const float4*)(wp + 4);
      bf16x8 b;
      b[0] = f2bf(w0.x); b[1] = f2bf(w0.y); b[2] = f2bf(w0.z); b[3] = f2bf(w0.w);
      b[4] = f2bf(w1.x); b[5] = f2bf(w1.y); b[6] = f2bf(w1.z); b[7] = f2bf(w1.w);
      Bf[c][t] = b;
    }
  }

  bf16x8 Af[4];
#pragma unroll
  for (int t = 0; t < 4; ++t) {
    Af[t] = *(const bf16x8*)(hb + (size_t)(m0 + r) * DD + t * 32 + g * 8);
  }

#pragma unroll
  for (int c = 0; c < 8; ++c) {
    f32x4 acc = {0.f, 0.f, 0.f, 0.f};
#pragma unroll
    for (int t = 0; t < 4; ++t) {
      acc = __builtin_amdgcn_mfma_f32_16x16x32_bf16(Af[t], Bf[c][t], acc, 0, 0, 0);
    }
#pragma unroll
    for (int q = 0; q < 4; ++q) {
      int row = m0 + g * 4 + q;
      float v = acc[q] + bs[c];
      out[(size_t)row * DD + c * 16 + r] = v > 0.f ? v : 0.f;
    }
  }
}

extern "C" void kernel_launch(void* const* d_in, const int* in_sizes, int n_in,
                              void* d_out, int out_size, void* d_ws, size_t ws_size,
                              hipStream_t stream) {
  const float* feature = (const float*)d_in[0];
  const int*   src     = (const int*)d_in[1];
  const int*   dst     = (const int*)d_in[2];
  const float* weight  = (const float*)d_in[3];
  const float* bias    = (const float*)d_in[4];
  float* out = (float*)d_out;

  // ws (ints): cnt2[76636 pad 76640] bsum[80] row_start[50001 pad 50004] | hb bf16 (12.8MB)
  int* cnt2      = (int*)d_ws;
  int* bsum      = cnt2 + 76640;
  int* row_start = bsum + 80;            // int offset 76720
  unsigned short* hb = (unsigned short*)(cnt2 + 126724);  // byte 506896, 16B aligned

  // d_out scratch (ints): ss[E] csr[E] fb(3.2M ints = 12.8MB) -- exactly 25.6MB
  unsigned int* ss = (unsigned int*)d_out;
  int* csr = (int*)d_out + EE;
  unsigned short* fb = (unsigned short*)((int*)d_out + 2 * EE);

  feat2bf_kernel<<<(NN * DD / 4 + 255) / 256, 256, 0, stream>>>(feature, fb);
  p1b<<<98, 256, 0, stream>>>(dst, cnt2);
  sA_bsum<<<NSA, 1024, 0, stream>>>(cnt2, bsum, NCNT);
  p2_scan<<<1, 1024, 0, stream>>>(bsum, bsum, NSA);
  sC_apply<<<NSA, 1024, 0, stream>>>(cnt2, bsum, NCNT);
  p3b<<<98, 256, 0, stream>>>(src, dst, cnt2, ss);
  fillL2<<<GSB, 1024, 0, stream>>>(ss, cnt2, csr, row_start);
  aggregate_bf16<<<(NN + 3) / 4, 256, 0, stream>>>(fb, row_start, csr, hb);
  mfma_gemm_kernel<<<(NSTRIP + 3) / 4, 256, 0, stream>>>((const short*)hb, weight, bias, out);
}

// Round 16
// 109.330 us; speedup vs baseline: 2.7287x; 1.2822x over previous
//
#include <hip/hip_runtime.h>

// GCN: h = mean-aggregate(feature over incoming edges, fallback feature if deg==0)
//      out = relu(h @ W^T + b)
// N=50000 nodes, E=1600000 edges, D=128.
// R16: GEMM v2 -- W staged once per block as bf16 fragments in LDS (32KB),
//      4 waves x 2 strips each; kills the per-wave 64KB W prologue (R15: 50us,
//      MfmaUtil 1.1%). CSR build unchanged from R15.

#define NN 50000
#define EE 1600000
#define DD 128
#define NSTRIP 3125    // 50000 / 16
#define GSB 196        // sub-buckets of 256 nodes (50000 = 195*256 + 80)
#define CH2 4096       // edges per wave-chunk
#define NW2 391        // ceil(EE / CH2)
#define NCNT (GSB * NW2)   // 76636
#define NSA 75         // ceil(NCNT / 1024)
#define WCAP 12288     // LDS window (ints); mean need 8163

typedef __attribute__((ext_vector_type(8))) short bf16x8;
typedef __attribute__((ext_vector_type(8))) unsigned short u16x8;
typedef __attribute__((ext_vector_type(4))) float f32x4;

static __device__ __forceinline__ short f2bf(float f) {
  union { float f; unsigned u; } x; x.f = f;
  unsigned r = (x.u + 0x7FFF + ((x.u >> 16) & 1)) >> 16;
  return (short)(r & 0xFFFF);
}

// ---- p1b: per-wave-chunk 196-way counts (LDS counters, low contention) ----
__global__ __launch_bounds__(256) void p1b(
    const int* __restrict__ dst, int* __restrict__ cnt2) {
  __shared__ int cnt[4][GSB];
  const int wv = threadIdx.x >> 6, lane = threadIdx.x & 63;
  const int w = blockIdx.x * 4 + wv;
  const bool act = (w < NW2);
  for (int i = lane; i < GSB; i += 64) cnt[wv][i] = 0;
  __syncthreads();
  if (act) {
    const int base = w * CH2;
#pragma unroll 4
    for (int it = 0; it < 16; ++it) {
      int e0 = base + it * 256 + lane * 4;
      if (e0 < EE) {
        int4 d4 = *(const int4*)(dst + e0);
        atomicAdd(&cnt[wv][((unsigned)d4.x) >> 8], 1);
        atomicAdd(&cnt[wv][((unsigned)d4.y) >> 8], 1);
        atomicAdd(&cnt[wv][((unsigned)d4.z) >> 8], 1);
        atomicAdd(&cnt[wv][((unsigned)d4.w) >> 8], 1);
      }
    }
  }
  __syncthreads();
  if (act) {
    for (int i = lane; i < GSB; i += 64) cnt2[i * NW2 + w] = cnt[wv][i];
  }
}

// ---- sA: per-block sums of cnt2 ----
__global__ __launch_bounds__(1024) void sA_bsum(
    const int* __restrict__ in, int* __restrict__ bsum, int n) {
  __shared__ int ws[16];
  int i = blockIdx.x * 1024 + threadIdx.x;
  int v = (i < n) ? in[i] : 0;
#pragma unroll
  for (int d = 1; d < 64; d <<= 1) v += __shfl_xor(v, d, 64);
  int wv = threadIdx.x >> 6, lane = threadIdx.x & 63;
  if (lane == 0) ws[wv] = v;
  __syncthreads();
  if (threadIdx.x == 0) {
    int s = 0;
#pragma unroll
    for (int k = 0; k < 16; ++k) s += ws[k];
    bsum[blockIdx.x] = s;
  }
}

// ---- generic single-block exclusive scan (in-place safe) ----
__global__ __launch_bounds__(1024) void p2_scan(
    const int* __restrict__ in, int* __restrict__ out, int n) {
  __shared__ int ws[16];
  __shared__ int s_off;
  const int wv = threadIdx.x >> 6, lane = threadIdx.x & 63;
  if (threadIdx.x == 0) s_off = 0;
  __syncthreads();
  for (int base = 0; base < n; base += 1024) {
    int i = base + threadIdx.x;
    int v = (i < n) ? in[i] : 0;
    int x = v;
#pragma unroll
    for (int d = 1; d < 64; d <<= 1) { int t = __shfl_up(x, d, 64); if (lane >= d) x += t; }
    if (lane == 63) ws[wv] = x;
    __syncthreads();
    if (threadIdx.x < 16) {
      int w = ws[threadIdx.x];
#pragma unroll
      for (int d = 1; d < 16; d <<= 1) { int t = __shfl_up(w, d, 16); if (threadIdx.x >= d) w += t; }
      ws[threadIdx.x] = w;
    }
    __syncthreads();
    int off = s_off + ((wv == 0) ? 0 : ws[wv - 1]);
    if (i < n) out[i] = off + x - v;
    __syncthreads();
    if (threadIdx.x == 0) s_off += ws[15];
    __syncthreads();
  }
}

// ---- sC: apply block offsets (exclusive scan finalize, in-place) ----
__global__ __launch_bounds__(1024) void sC_apply(
    int* __restrict__ data, const int* __restrict__ bsum, int n) {
  __shared__ int ws[16];
  int i = blockIdx.x * 1024 + threadIdx.x;
  int wv = threadIdx.x >> 6, lane = threadIdx.x & 63;
  int v = (i < n) ? data[i] : 0;
  int x = v;
#pragma unroll
  for (int d = 1; d < 64; d <<= 1) { int t = __shfl_up(x, d, 64); if (lane >= d) x += t; }
  if (lane == 63) ws[wv] = x;
  __syncthreads();
  if (threadIdx.x < 16) {
    int w = ws[threadIdx.x];
#pragma unroll
    for (int d = 1; d < 16; d <<= 1) { int t = __shfl_up(w, d, 16); if (threadIdx.x >= d) w += t; }
    ws[threadIdx.x] = w;
  }
  __syncthreads();
  int off = bsum[blockIdx.x] + ((wv == 0) ? 0 : ws[wv - 1]);
  if (i < n) data[i] = off + x - v;
}

// ---- p3b: 196-way partition of packed edges (per-wave LDS cursors) ----
__global__ __launch_bounds__(256) void p3b(
    const int* __restrict__ src, const int* __restrict__ dst,
    const int* __restrict__ off2, unsigned int* __restrict__ ss) {
  __shared__ int cur[4][GSB];
  const int wv = threadIdx.x >> 6, lane = threadIdx.x & 63;
  const int w = blockIdx.x * 4 + wv;
  const bool act = (w < NW2);
  if (act) {
    for (int i = lane; i < GSB; i += 64) cur[wv][i] = off2[i * NW2 + w];
  }
  __syncthreads();
  if (act) {
    const int base = w * CH2;
#pragma unroll 2
    for (int it = 0; it < 16; ++it) {
      int e0 = base + it * 256 + lane * 4;
      if (e0 < EE) {
        int4 s4 = *(const int4*)(src + e0);
        int4 d4 = *(const int4*)(dst + e0);
        {
          int p = atomicAdd(&cur[wv][((unsigned)d4.x) >> 8], 1);
          ss[p] = (((unsigned)d4.x) << 16) | (unsigned)s4.x;
        }
        {
          int p = atomicAdd(&cur[wv][((unsigned)d4.y) >> 8], 1);
          ss[p] = (((unsigned)d4.y) << 16) | (unsigned)s4.y;
        }
        {
          int p = atomicAdd(&cur[wv][((unsigned)d4.z) >> 8], 1);
          ss[p] = (((unsigned)d4.z) << 16) | (unsigned)s4.z;
        }
        {
          int p = atomicAdd(&cur[wv][((unsigned)d4.w) >> 8], 1);
          ss[p] = (((unsigned)d4.w) << 16) | (unsigned)s4.w;
        }
      }
    }
  }
}

// ---- fillL2: per-sub-bucket CSR build + row_start (reads ONLY own region) ----
__global__ __launch_bounds__(1024) void fillL2(
    const unsigned int* __restrict__ ss, const int* __restrict__ off2,
    int* __restrict__ csr, int* __restrict__ row_start) {
  __shared__ int win[WCAP];
  __shared__ int cur[256];
  __shared__ int rs[257];
  __shared__ int wsum2[4];
  const int g    = blockIdx.x;
  const int lo   = g * 256;
  const int nloc = (NN - lo < 256) ? (NN - lo) : 256;
  const int ebase = off2[g * NW2];
  const int eend  = (g < GSB - 1) ? off2[(g + 1) * NW2] : EE;
  const int T = eend - ebase;

  if (threadIdx.x < 256) cur[threadIdx.x] = 0;
  __syncthreads();

  for (int e = ebase + threadIdx.x; e < eend; e += 1024) {
    atomicAdd(&cur[(ss[e] >> 16) & 255], 1);
  }
  __syncthreads();

  int x = 0;
  if (threadIdx.x < 256) {
    const int lane = threadIdx.x & 63;
    x = cur[threadIdx.x];
#pragma unroll
    for (int d = 1; d < 64; d <<= 1) { int t = __shfl_up(x, d, 64); if (lane >= d) x += t; }
    if (lane == 63) wsum2[threadIdx.x >> 6] = x;
  }
  __syncthreads();
  if (threadIdx.x < 256) {
    const int wv2 = threadIdx.x >> 6;
    int pre = 0;
#pragma unroll
    for (int k = 0; k < 4; ++k) pre += (k < wv2) ? wsum2[k] : 0;
    rs[threadIdx.x + 1] = pre + x;
    if (threadIdx.x == 0) rs[0] = 0;
    cur[threadIdx.x] = 0;
  }
  __syncthreads();

  if (threadIdx.x <= nloc) row_start[lo + threadIdx.x] = ebase + rs[threadIdx.x];

  if (T <= WCAP) {
    for (int e = ebase + threadIdx.x; e < eend; e += 1024) {
      unsigned pe = ss[e];
      int li = (pe >> 16) & 255;
      int p = atomicAdd(&cur[li], 1);
      win[rs[li] + p] = (int)(pe & 0xFFFFu);
    }
    __syncthreads();
    for (int i = threadIdx.x; i < T; i += 1024) csr[ebase + i] = win[i];
  } else {
    for (int e = ebase + threadIdx.x; e < eend; e += 1024) {
      unsigned pe = ss[e];
      int li = (pe >> 16) & 255;
      int p = atomicAdd(&cur[li], 1);
      csr[ebase + rs[li] + p] = (int)(pe & 0xFFFFu);
    }
  }
}

// ---- feat2bf: f32 feature -> bf16 table ----
__global__ __launch_bounds__(256) void feat2bf_kernel(
    const float* __restrict__ feature, unsigned short* __restrict__ fb) {
  int i = blockIdx.x * 256 + threadIdx.x;
  if (i < NN * DD / 4) {
    float4 v = ((const float4*)feature)[i];
    short4 o;
    o.x = f2bf(v.x); o.y = f2bf(v.y); o.z = f2bf(v.z); o.w = f2bf(v.w);
    ((short4*)fb)[i] = o;
  }
}

// ---- aggregate: wave per node, u16x8/lane, 16 lanes/row, 4 edges in flight ----
__global__ __launch_bounds__(256) void aggregate_bf16(
    const unsigned short* __restrict__ fb,
    const int* __restrict__ row_start,
    const int* __restrict__ csr_src,
    unsigned short* __restrict__ hb) {
  const int wave = threadIdx.x >> 6;
  const int lane = threadIdx.x & 63;
  int n = blockIdx.x * 4 + wave;
  if (n >= NN) return;

  const int start = row_start[n];
  const int end   = row_start[n + 1];
  const int deg   = end - start;
  const int q  = lane >> 4;
  const int sl = lane & 15;

  const u16x8* fp = (const u16x8*)fb;
  float acc[8];
#pragma unroll
  for (int j = 0; j < 8; ++j) acc[j] = 0.f;

#pragma unroll 4
  for (int e = start + q; e < end; e += 4) {
    int s = csr_src[e];
    u16x8 v = fp[(size_t)s * 16 + sl];
#pragma unroll
    for (int j = 0; j < 8; ++j) {
      union { unsigned u; float f; } c; c.u = ((unsigned)v[j]) << 16;
      acc[j] += c.f;
    }
  }
#pragma unroll
  for (int j = 0; j < 8; ++j) {
    acc[j] += __shfl_xor(acc[j], 16, 64);
    acc[j] += __shfl_xor(acc[j], 32, 64);
  }

  if (q == 0) {
    u16x8 hv;
    if (deg > 0) {
      float inv = 1.0f / (float)deg;
#pragma unroll
      for (int j = 0; j < 8; ++j) hv[j] = (unsigned short)f2bf(acc[j] * inv);
    } else {
      hv = fp[(size_t)n * 16 + sl];
    }
    ((u16x8*)hb)[(size_t)n * 16 + sl] = hv;
  }
}

// ---- GEMM v2: W staged in LDS as bf16 fragments; 4 waves x 2 strips/block ----
// LDS fragment layout: wfrag[(c*4+t)*64 + lane] = W[c*16+(lane&15)][t*32+(lane>>4)*8 ..+7]
__global__ __launch_bounds__(256) void mfma_gemm2(
    const short* __restrict__ hb,
    const float* __restrict__ weight,
    const float* __restrict__ bias,
    float* __restrict__ out) {
  __shared__ bf16x8 wfrag[2048];   // 32 KB
  __shared__ float  bias_l[DD];    // 512 B

  // cooperative staging: 2048 entries, 8 per thread
#pragma unroll
  for (int k = 0; k < 8; ++k) {
    int idx  = threadIdx.x * 8 + k;
    int ln   = idx & 63;
    int ct   = idx >> 6;          // 0..31
    int c    = ct >> 2;
    int t    = ct & 3;
    const float* wp = weight + (c * 16 + (ln & 15)) * DD + t * 32 + (ln >> 4) * 8;
    float4 w0 = *(const float4*)(wp);
    float4 w1 = *(const float4*)(wp + 4);
    bf16x8 b;
    b[0] = f2bf(w0.x); b[1] = f2bf(w0.y); b[2] = f2bf(w0.z); b[3] = f2bf(w0.w);
    b[4] = f2bf(w1.x); b[5] = f2bf(w1.y); b[6] = f2bf(w1.z); b[7] = f2bf(w1.w);
    wfrag[idx] = b;
  }
  if (threadIdx.x < DD) bias_l[threadIdx.x] = bias[threadIdx.x];
  __syncthreads();

  const int wave = threadIdx.x >> 6;
  const int lane = threadIdx.x & 63;
  const int r  = lane & 15;
  const int g  = lane >> 4;

#pragma unroll
  for (int s = 0; s < 2; ++s) {
    const int strip = blockIdx.x * 8 + wave * 2 + s;
    if (strip >= NSTRIP) continue;
    const int m0 = strip * 16;

    bf16x8 Af[4];
#pragma unroll
    for (int t = 0; t < 4; ++t) {
      Af[t] = *(const bf16x8*)(hb + (size_t)(m0 + r) * DD + t * 32 + g * 8);
    }

#pragma unroll
    for (int c = 0; c < 8; ++c) {
      f32x4 acc = {0.f, 0.f, 0.f, 0.f};
#pragma unroll
      for (int t = 0; t < 4; ++t) {
        acc = __builtin_amdgcn_mfma_f32_16x16x32_bf16(Af[t], wfrag[(c * 4 + t) * 64 + lane], acc, 0, 0, 0);
      }
      const float b = bias_l[c * 16 + r];
#pragma unroll
      for (int q = 0; q < 4; ++q) {
        int row = m0 + g * 4 + q;
        float v = acc[q] + b;
        out[(size_t)row * DD + c * 16 + r] = v > 0.f ? v : 0.f;
      }
    }
  }
}

extern "C" void kernel_launch(void* const* d_in, const int* in_sizes, int n_in,
                              void* d_out, int out_size, void* d_ws, size_t ws_size,
                              hipStream_t stream) {
  const float* feature = (const float*)d_in[0];
  const int*   src     = (const int*)d_in[1];
  const int*   dst     = (const int*)d_in[2];
  const float* weight  = (const float*)d_in[3];
  const float* bias    = (const float*)d_in[4];
  float* out = (float*)d_out;

  // ws (ints): cnt2[76636 pad 76640] bsum[80] row_start[50001 pad 50004] | hb bf16 (12.8MB)
  int* cnt2      = (int*)d_ws;
  int* bsum      = cnt2 + 76640;
  int* row_start = bsum + 80;
  unsigned short* hb = (unsigned short*)(cnt2 + 126724);  // byte 506896, 16B aligned

  // d_out scratch (ints): ss[E] csr[E] fb(3.2M ints = 12.8MB) -- exactly 25.6MB
  unsigned int* ss = (unsigned int*)d_out;
  int* csr = (int*)d_out + EE;
  unsigned short* fb = (unsigned short*)((int*)d_out + 2 * EE);

  feat2bf_kernel<<<(NN * DD / 4 + 255) / 256, 256, 0, stream>>>(feature, fb);
  p1b<<<98, 256, 0, stream>>>(dst, cnt2);
  sA_bsum<<<NSA, 1024, 0, stream>>>(cnt2, bsum, NCNT);
  p2_scan<<<1, 1024, 0, stream>>>(bsum, bsum, NSA);
  sC_apply<<<NSA, 1024, 0, stream>>>(cnt2, bsum, NCNT);
  p3b<<<98, 256, 0, stream>>>(src, dst, cnt2, ss);
  fillL2<<<GSB, 1024, 0, stream>>>(ss, cnt2, csr, row_start);
  aggregate_bf16<<<(NN + 3) / 4, 256, 0, stream>>>(fb, row_start, csr, hb);
  mfma_gemm2<<<(NSTRIP + 7) / 8, 256, 0, stream>>>((const short*)hb, weight, bias, out);
}